// Round 1
// baseline (137.589 us; speedup 1.0000x reference)
//
#include <hip/hip_runtime.h>
#include <hip/hip_bf16.h>
#include <math.h>

#define LOG2PI_F 1.8378770664093453f

typedef __attribute__((ext_vector_type(8))) short bf16x8;
typedef __attribute__((ext_vector_type(4))) float f32x4;
typedef __attribute__((ext_vector_type(16))) float f32x16;

static __device__ inline short f2bf(float x) {
  __hip_bfloat16 h = __float2bfloat16(x);
  return *reinterpret_cast<short*>(&h);
}
// hot-path f32 pair -> packed bf16x2 in one instruction (gfx950 HW RNE)
static __device__ inline unsigned cvtpk(float lo, float hi) {
  unsigned r;
  asm("v_cvt_pk_bf16_f32 %0, %1, %2" : "=v"(r) : "v"(lo), "v"(hi));
  return r;
}
static __device__ inline f32x4 mfma16(bf16x8 a, bf16x8 b, f32x4 c) {
  return __builtin_amdgcn_mfma_f32_16x16x32_bf16(a, b, c, 0, 0, 0);
}
static __device__ inline f32x16 mfma32(bf16x8 a, bf16x8 b, f32x16 c) {
  return __builtin_amdgcn_mfma_f32_32x32x16_bf16(a, b, c, 0, 0, 0);
}

// ---------------- K0: WTbf[k'][k] = bf16(softmax_row_k(tl)[k']) -------------
__global__ __launch_bounds__(64) void mmm_w_kernel(
    const float* __restrict__ tl, short* __restrict__ WTbf) {
  int r = blockIdx.x, lane = threadIdx.x;
  float v = tl[r * 64 + lane];
  float mx = v;
  #pragma unroll
  for (int off = 1; off < 64; off <<= 1) mx = fmaxf(mx, __shfl_xor(mx, off));
  float e = expf(v - mx);
  float s = e;
  #pragma unroll
  for (int off = 1; off < 64; off <<= 1) s += __shfl_xor(s, off);
  WTbf[lane * 64 + r] = f2bf(e / s);
}

// ---------------- K1: prep Gt bf16 [512][256] + const_c[512] ----------------
__global__ __launch_bounds__(128) void mmm_prep_kernel(
    const float* __restrict__ means, const float* __restrict__ log_vars,
    const float* __restrict__ weight_logits,
    short* __restrict__ Gt, float* __restrict__ const_c) {
  int sm = blockIdx.x;
  int s = sm >> 3, m = sm & 7;
  int d = threadIdx.x;
  float lv = log_vars[sm * 128 + d];
  float iv = expf(-lv);
  float mu = means[sm * 128 + d];
  float miv = mu * iv;
  Gt[sm * 256 + d] = f2bf(miv);
  Gt[sm * 256 + 128 + d] = f2bf(-0.5f * iv);
  float v = mu * miv + lv;
  #pragma unroll
  for (int off = 1; off < 64; off <<= 1) v += __shfl_xor(v, off);
  __shared__ float red[2];
  if ((d & 63) == 0) red[d >> 6] = v;
  __syncthreads();
  if (d == 0) {
    float tot = red[0] + red[1];
    float wl[8];
    float mx = -3.4e38f;
    #pragma unroll
    for (int j = 0; j < 8; ++j) { wl[j] = weight_logits[s * 8 + j]; mx = fmaxf(mx, wl[j]); }
    float sum = 0.f;
    #pragma unroll
    for (int j = 0; j < 8; ++j) sum += expf(wl[j] - mx);
    float lmw = wl[m] - mx - logf(sum);
    const_c[sm] = -0.5f * (tot + 128.0f * LOG2PI_F) + lmw;
  }
}

// ---------------- K2: prep XeP bf16 packed [8 kb2][32768 bt][32 kk] ----------
__global__ __launch_bounds__(256) void mmm_prepxe_kernel(
    const float* __restrict__ X, short* __restrict__ XeP) {
  int q = blockIdx.x >> 7;
  int bt = ((blockIdx.x & 127) << 8) + threadIdx.x;
  const float4* src = (const float4*)(X + (size_t)bt * 128 + q * 32);
  float xv[32];
  #pragma unroll
  for (int i = 0; i < 8; ++i) {
    float4 v = src[i];
    xv[4 * i] = v.x; xv[4 * i + 1] = v.y; xv[4 * i + 2] = v.z; xv[4 * i + 3] = v.w;
  }
  size_t base1 = ((size_t)q * 32768 + bt) * 32;
  size_t base2 = ((size_t)(q + 4) * 32768 + bt) * 32;
  int bx = bt & 3;
  #pragma unroll
  for (int g = 0; g < 4; ++g) {
    bf16x8 t1, t2;
    #pragma unroll
    for (int j = 0; j < 8; ++j) {
      float x = xv[g * 8 + j];
      t1[j] = f2bf(x);
      t2[j] = f2bf(x * x);
    }
    int gs = (g ^ bx) * 8;
    *(bf16x8*)&XeP[base1 + gs] = t1;
    *(bf16x8*)&XeP[base2 + gs] = t2;
  }
}

// ---------------- K3: MFMA emission GEMM, C[sm=512][bt=64-tile] ------------
__global__ __launch_bounds__(512) void mmm_emis_kernel(
    const short* __restrict__ Gt, const short* __restrict__ XeP,
    const float* __restrict__ const_c,
    float* __restrict__ ehat, float* __restrict__ cmax) {
  __shared__ __align__(16) short Bt[16384];  // 32 KB
  __shared__ __align__(16) float ccs[512];
  __shared__ float wavemax[8][64];
  __shared__ float colmax[64];
  int tid = threadIdx.x;
  int w = tid >> 6, lane = tid & 63, lr = lane & 15, lg = lane >> 4;

  ccs[tid] = const_c[tid];

  bf16x8 gf[4][8];
  #pragma unroll
  for (int rt = 0; rt < 4; ++rt) {
    int row = w * 64 + rt * 16 + lr;
    #pragma unroll
    for (int kc = 0; kc < 8; ++kc)
      gf[rt][kc] = *(const bf16x8*)&Gt[row * 256 + kc * 32 + lg * 8];
  }

  uint4 sreg[4];
  {
    size_t bt0 = (size_t)blockIdx.x * 64;
    #pragma unroll
    for (int r = 0; r < 4; ++r) {
      int ofs = r * 8192 + tid * 16;
      int kb2 = ofs >> 12, rem = ofs & 4095;
      sreg[r] = *(const uint4*)((const char*)XeP + ((size_t)kb2 * 32768 + bt0) * 64 + rem);
    }
  }

  for (int it = 0; it < 2; ++it) {
    int bt0 = (blockIdx.x + it * 256) * 64;
    __syncthreads();
    #pragma unroll
    for (int r = 0; r < 4; ++r)
      *(uint4*)((char*)Bt + r * 8192 + tid * 16) = sreg[r];
    __syncthreads();
    if (it == 0) {
      size_t bt0n = ((size_t)blockIdx.x + 256) * 64;
      #pragma unroll
      for (int r = 0; r < 4; ++r) {
        int ofs = r * 8192 + tid * 16;
        int kb2 = ofs >> 12, rem = ofs & 4095;
        sreg[r] = *(const uint4*)((const char*)XeP + ((size_t)kb2 * 32768 + bt0n) * 64 + rem);
      }
    }

    f32x4 acc[4][4];
    #pragma unroll
    for (int rt = 0; rt < 4; ++rt)
      #pragma unroll
      for (int ct = 0; ct < 4; ++ct)
        acc[rt][ct] = (f32x4){0.f, 0.f, 0.f, 0.f};

    #pragma unroll
    for (int kc = 0; kc < 8; ++kc) {
      bf16x8 bfr[4];
      #pragma unroll
      for (int ct = 0; ct < 4; ++ct) {
        int btL = ct * 16 + lr;
        bfr[ct] = *(const bf16x8*)&Bt[kc * 2048 + btL * 32 + ((lg ^ (btL & 3)) * 8)];
      }
      #pragma unroll
      for (int rt = 0; rt < 4; ++rt)
        #pragma unroll
        for (int ct = 0; ct < 4; ++ct)
          acc[rt][ct] = mfma16(gf[rt][kc], bfr[ct], acc[rt][ct]);
    }

    float lse[4][4];
    #pragma unroll
    for (int rt = 0; rt < 4; ++rt) {
      f32x4 cc = *(f32x4*)&ccs[w * 64 + rt * 16 + lg * 4];
      #pragma unroll
      for (int ct = 0; ct < 4; ++ct) {
        f32x4 v = acc[rt][ct] + cc;
        float mx = fmaxf(fmaxf(v[0], v[1]), fmaxf(v[2], v[3]));
        mx = fmaxf(mx, __shfl_xor(mx, 16));
        float sum = expf(v[0] - mx) + expf(v[1] - mx) + expf(v[2] - mx) + expf(v[3] - mx);
        sum += __shfl_xor(sum, 16);
        lse[rt][ct] = mx + logf(sum);
      }
    }
    #pragma unroll
    for (int ct = 0; ct < 4; ++ct) {
      float cm = fmaxf(fmaxf(lse[0][ct], lse[1][ct]), fmaxf(lse[2][ct], lse[3][ct]));
      cm = fmaxf(cm, __shfl_xor(cm, 32));
      if (lg == 0) wavemax[w][ct * 16 + lr] = cm;
    }
    __syncthreads();
    if (w == 0) {
      float cm = wavemax[0][lane];
      #pragma unroll
      for (int ww = 1; ww < 8; ++ww) cm = fmaxf(cm, wavemax[ww][lane]);
      colmax[lane] = cm;
      cmax[(size_t)bt0 + lane] = cm;
    }
    __syncthreads();
    #pragma unroll
    for (int ct = 0; ct < 4; ++ct) {
      float cm = colmax[ct * 16 + lr];
      #pragma unroll
      for (int rt = 0; rt < 4; ++rt) {
        float v = expf(lse[rt][ct] - cm);
        if (!(lg & 1))
          ehat[((size_t)bt0 + ct * 16 + lr) * 64 + (w * 8 + rt * 2 + (lg >> 1))] = v;
      }
    }
  }
}

// ---------------- K4: per-chunk product, 32x32 MFMA + permlane32_swap -------
// 256 chunks x 16 steps (was 128x32): doubles resident waves (8->16/CU) and
// halves each block's serial chain. Wave wv owns cols [wv*32, wv*32+32).
// Step: C' = diag(e) * W^T * C.  C->B redistribution = one permlane32_swap
// per (quad-pair, p). bf16 repack via HW v_cvt_pk_bf16_f32 (1 instr/pair).
__global__ __launch_bounds__(128) void mmm_chunk_kernel(
    const short* __restrict__ WTbf, const float* __restrict__ ehat,
    const float* __restrict__ cmax, float* __restrict__ NT,
    float* __restrict__ aux) {
  int chunk = blockIdx.x, b = blockIdx.y;
  int tid = threadIdx.x;
  int wv = tid >> 6, lane = tid & 63;
  int l31 = lane & 31, hi = lane >> 5;

  // A = W^T: af[wi][kb], row = wi*32+l31, k = kb*16 + hi*8 + j
  bf16x8 af[2][4];
  #pragma unroll
  for (int wi = 0; wi < 2; ++wi)
    #pragma unroll
    for (int kb = 0; kb < 4; ++kb)
      af[wi][kb] = *(const bf16x8*)&WTbf[(wi * 32 + l31) * 64 + kb * 16 + hi * 8];

  // state: C0/C1 (N = I). reg r -> row (r&3)+8*(r>>2)+4*hi, col wv*32+l31
  f32x16 c0, c1;
  #pragma unroll
  for (int r = 0; r < 16; ++r) {
    int row = (r & 3) + 8 * (r >> 2) + 4 * hi;
    c0[r] = (wv == 0 && row == l31) ? 1.f : 0.f;
    c1[r] = (wv == 1 && row == l31) ? 1.f : 0.f;
  }

  int t0 = (chunk == 0) ? 1 : chunk * 16;
  int nsteps = (chunk == 0) ? 15 : 16;
  const float* eb = ehat + (size_t)b * 4096 * 64;

  // packed state: P[cm][q][p] = rows 32cm+8q+4hi+{2p,2p+1} at this col
  unsigned P[2][4][2];
  #pragma unroll
  for (int q = 0; q < 4; ++q)
    #pragma unroll
    for (int p = 0; p < 2; ++p) {
      P[0][q][p] = cvtpk(c0[4 * q + 2 * p], c0[4 * q + 2 * p + 1]);
      P[1][q][p] = cvtpk(c1[4 * q + 2 * p], c1[4 * q + 2 * p + 1]);
    }

  float logscale = 0.f;
  f32x4 ecur[2][4], enxt[2][4];
  #pragma unroll
  for (int cm = 0; cm < 2; ++cm)
    #pragma unroll
    for (int q = 0; q < 4; ++q)
      ecur[cm][q] = *(const f32x4*)&eb[(size_t)t0 * 64 + cm * 32 + q * 8 + hi * 4];

  for (int it = 0; it < nsteps; ++it) {
    if (it + 1 < nsteps) {
      #pragma unroll
      for (int cm = 0; cm < 2; ++cm)
        #pragma unroll
        for (int q = 0; q < 4; ++q)
          enxt[cm][q] = *(const f32x4*)&eb[(size_t)(t0 + it + 1) * 64 + cm * 32 + q * 8 + hi * 4];
    }

    // B[kb]: k = kb*16 + 8*hi + j. One swap per (p): low word from vsrc',
    // high word from vdst'.
    bf16x8 B[4];
    #pragma unroll
    for (int kb = 0; kb < 4; ++kb) {
      int cm = kb >> 1, kbl = kb & 1;
      int4 wrd;
      #pragma unroll
      for (int p = 0; p < 2; ++p) {
        unsigned avv = P[cm][2 * kbl + 1][p];
        unsigned bvv = P[cm][2 * kbl][p];
        asm("v_permlane32_swap_b32 %0, %1" : "+v"(avv), "+v"(bvv));
        if (p == 0) { wrd.x = (int)bvv; wrd.z = (int)avv; }
        else        { wrd.y = (int)bvv; wrd.w = (int)avv; }
      }
      B[kb] = *(bf16x8*)&wrd;
    }

    f32x16 d0, d1;
    #pragma unroll
    for (int r = 0; r < 16; ++r) { d0[r] = 0.f; d1[r] = 0.f; }
    #pragma unroll
    for (int kb = 0; kb < 4; ++kb) {
      d0 = mfma32(af[0][kb], B[kb], d0);
      d1 = mfma32(af[1][kb], B[kb], d1);
    }

    // e-scale rows: reg 4q+s -> row 32cm+8q+4hi+s
    #pragma unroll
    for (int q = 0; q < 4; ++q)
      #pragma unroll
      for (int s = 0; s < 4; ++s) {
        c0[4 * q + s] = d0[4 * q + s] * ecur[0][q][s];
        c1[4 * q + s] = d1[4 * q + s] * ecur[1][q][s];
      }

    if ((it & 7) == 7) {  // per-wave (32-col strip) rescale
      float m = 0.f;
      #pragma unroll
      for (int r = 0; r < 16; ++r) m = fmaxf(m, fmaxf(c0[r], c1[r]));
      #pragma unroll
      for (int off = 1; off < 64; off <<= 1) m = fmaxf(m, __shfl_xor(m, off));
      float inv = 1.0f / m;
      #pragma unroll
      for (int r = 0; r < 16; ++r) { c0[r] *= inv; c1[r] *= inv; }
      logscale += logf(m);
    }

    #pragma unroll
    for (int q = 0; q < 4; ++q)
      #pragma unroll
      for (int p = 0; p < 2; ++p) {
        P[0][q][p] = cvtpk(c0[4 * q + 2 * p], c0[4 * q + 2 * p + 1]);
        P[1][q][p] = cvtpk(c1[4 * q + 2 * p], c1[4 * q + 2 * p + 1]);
      }
    #pragma unroll
    for (int cm = 0; cm < 2; ++cm)
      #pragma unroll
      for (int q = 0; q < 4; ++q) ecur[cm][q] = enxt[cm][q];
  }

  // store N_c f32 row-major [row][col]
  float* No = NT + (((size_t)b * 256 + chunk) << 12);
  #pragma unroll
  for (int r = 0; r < 16; ++r) {
    int row = (r & 3) + 8 * (r >> 2) + 4 * hi;
    No[row * 64 + wv * 32 + l31] = c0[r];
    No[(32 + row) * 64 + wv * 32 + l31] = c1[r];
  }

  // aux[b][chunk][wv] = sum cmax + per-strip logscale (strip = 32 cols)
  float cs = (lane < nsteps) ? cmax[(size_t)b * 4096 + t0 + lane] : 0.f;
  #pragma unroll
  for (int off = 1; off < 64; off <<= 1) cs += __shfl_xor(cs, off);
  if (lane == 0) aux[(((size_t)b * 256 + chunk) << 1) + wv] = cs + logscale;
}

// ---------------- K5: merge 16 chunks -> group matrix (16 groups/batch) -----
// Q' = N_cc * Q; per-32-col-strip scales of N_cc folded into A (k = column).
__global__ __launch_bounds__(256) void mmm_merge_kernel(
    const float* __restrict__ NT, const float* __restrict__ aux,
    float* __restrict__ G2T, float* __restrict__ auxg) {
  int g = blockIdx.x, b = blockIdx.y;
  int tid = threadIdx.x;
  int w = tid >> 6, lane = tid & 63;
  int wi = w >> 1, wj = w & 1;
  int lr = lane & 15, lg = lane >> 4;

  __shared__ __align__(16) short L[2][4096];
  __shared__ float wmax[4];

  for (int idx = tid; idx < 4096; idx += 256) {
    int j = idx >> 6, k = idx & 63;
    L[0][idx ^ ((j & 7) << 3)] = (j == k) ? (short)0x3F80 : (short)0;
  }
  __syncthreads();

  int cbase = b * 256 + g * 16;

  float logscale = 0.f;
  int cur = 0;
  f32x4 acc[2][2];

  f32x4 apre[2][2][2];
  {
    const float* Mc = NT + ((size_t)cbase << 12);
    #pragma unroll
    for (int rt = 0; rt < 2; ++rt)
      #pragma unroll
      for (int kc = 0; kc < 2; ++kc) {
        const float* src = Mc + (wi * 32 + rt * 16 + lr) * 64 + kc * 32 + lg * 8;
        apre[rt][kc][0] = *(const f32x4*)src;
        apre[rt][kc][1] = *(const f32x4*)(src + 4);
      }
  }

  for (int cc = 0; cc < 16; ++cc) {
    f32x4 acur[2][2][2];
    #pragma unroll
    for (int rt = 0; rt < 2; ++rt)
      #pragma unroll
      for (int kc = 0; kc < 2; ++kc) {
        acur[rt][kc][0] = apre[rt][kc][0];
        acur[rt][kc][1] = apre[rt][kc][1];
      }
    if (cc < 15) {
      const float* Mc = NT + ((size_t)(cbase + cc + 1) << 12);
      #pragma unroll
      for (int rt = 0; rt < 2; ++rt)
        #pragma unroll
        for (int kc = 0; kc < 2; ++kc) {
          const float* src = Mc + (wi * 32 + rt * 16 + lr) * 64 + kc * 32 + lg * 8;
          apre[rt][kc][0] = *(const f32x4*)src;
          apre[rt][kc][1] = *(const f32x4*)(src + 4);
        }
    }

    // per-strip (32-col) scale factors of N_cc; contraction k = column
    float a0 = aux[((cbase + cc) << 1) + 0];
    float a1 = aux[((cbase + cc) << 1) + 1];
    float ref = fmaxf(a0, a1);
    float fk0 = expf(a0 - ref);
    float fk1 = expf(a1 - ref);
    logscale += ref;

    bf16x8 afr[2][2];
    #pragma unroll
    for (int rt = 0; rt < 2; ++rt)
      #pragma unroll
      for (int kc = 0; kc < 2; ++kc) {
        float fk = kc ? fk1 : fk0;
        bf16x8 f;
        #pragma unroll
        for (int u = 0; u < 4; ++u) {
          f[u] = f2bf(acur[rt][kc][0][u] * fk);
          f[4 + u] = f2bf(acur[rt][kc][1][u] * fk);
        }
        afr[rt][kc] = f;
      }

    bf16x8 bfr[2][2];
    #pragma unroll
    for (int ct = 0; ct < 2; ++ct) {
      int j = wj * 32 + ct * 16 + lr;
      int sw = (j & 7) << 3;
      #pragma unroll
      for (int kc = 0; kc < 2; ++kc)
        bfr[ct][kc] = *(const bf16x8*)&L[cur][(j * 64 + kc * 32 + lg * 8) ^ sw];
    }

    #pragma unroll
    for (int rt = 0; rt < 2; ++rt)
      #pragma unroll
      for (int ct = 0; ct < 2; ++ct) {
        f32x4 c = {0.f, 0.f, 0.f, 0.f};
        c = mfma16(afr[rt][0], bfr[ct][0], c);
        c = mfma16(afr[rt][1], bfr[ct][1], c);
        acc[rt][ct] = c;
      }

    float m = 0.f;
    #pragma unroll
    for (int rt = 0; rt < 2; ++rt)
      #pragma unroll
      for (int ct = 0; ct < 2; ++ct)
        #pragma unroll
        for (int r = 0; r < 4; ++r) m = fmaxf(m, acc[rt][ct][r]);
    #pragma unroll
    for (int off = 1; off < 64; off <<= 1) m = fmaxf(m, __shfl_xor(m, off));
    if (lane == 0) wmax[w] = m;
    __syncthreads();
    m = fmaxf(fmaxf(wmax[0], wmax[1]), fmaxf(wmax[2], wmax[3]));
    float inv = 1.0f / m;
    #pragma unroll
    for (int rt = 0; rt < 2; ++rt)
      #pragma unroll
      for (int ct = 0; ct < 2; ++ct) acc[rt][ct] *= inv;
    logscale += logf(m);

    int nxt = cur ^ 1;
    #pragma unroll
    for (int rt = 0; rt < 2; ++rt)
      #pragma unroll
      for (int ct = 0; ct < 2; ++ct)
        #pragma unroll
        for (int r = 0; r < 4; ++r) {
          int row = wi * 32 + rt * 16 + lg * 4 + r;
          int col = wj * 32 + ct * 16 + lr;
          L[nxt][(col * 64 + row) ^ ((col & 7) << 3)] = f2bf(acc[rt][ct][r]);
        }
    __syncthreads();
    cur = nxt;
  }

  float* Mo = G2T + (((size_t)b * 16 + g) << 12);
  #pragma unroll
  for (int rt = 0; rt < 2; ++rt)
    #pragma unroll
    for (int ct = 0; ct < 2; ++ct)
      #pragma unroll
      for (int r = 0; r < 4; ++r) {
        int row = wi * 32 + rt * 16 + lg * 4 + r;
        int col = wj * 32 + ct * 16 + lr;
        Mo[row * 64 + col] = acc[rt][ct][r];
      }

  if (w == 0 && lane == 0) auxg[b * 16 + g] = logscale;
}

// ---------------- K6: final combine (16 group matrices per batch) -----------
__global__ __launch_bounds__(64) void mmm_combine_kernel(
    const float* __restrict__ pi_logits, const float* __restrict__ ehat,
    const float* __restrict__ cmax, const float* __restrict__ G2T,
    const float* __restrict__ auxg, float* __restrict__ out) {
  int b = blockIdx.x, lane = threadIdx.x;
  __shared__ __align__(16) float alds[64];

  float pv = pi_logits[lane];
  float mx = pv;
  #pragma unroll
  for (int off = 1; off < 64; off <<= 1) mx = fmaxf(mx, __shfl_xor(mx, off));
  float pe = expf(pv - mx);
  float ps = pe;
  #pragma unroll
  for (int off = 1; off < 64; off <<= 1) ps += __shfl_xor(ps, off);

  float a = (pe / ps) * ehat[(size_t)b * 4096 * 64 + lane];
  double logtot = (double)cmax[(size_t)b * 4096];
  alds[lane] = a;
  __builtin_amdgcn_wave_barrier();

  for (int g = 0; g < 16; ++g) {
    const float* Mc = G2T + (((size_t)b * 16 + g) << 12) + lane * 64;
    f32x4 a4 = {0.f, 0.f, 0.f, 0.f};
    #pragma unroll
    for (int i = 0; i < 64; i += 4) {
      f32x4 mv = *(const f32x4*)&Mc[i];
      f32x4 av = *(const f32x4*)&alds[i];
      a4 += mv * av;
    }
    float acc = (a4[0] + a4[1]) + (a4[2] + a4[3]);
    float s = acc;
    #pragma unroll
    for (int off = 1; off < 64; off <<= 1) s += __shfl_xor(s, off);
    logtot += (double)(auxg[b * 16 + g] + logf(s));
    float an = acc / s;
    __builtin_amdgcn_wave_barrier();
    alds[lane] = an;
    __builtin_amdgcn_wave_barrier();
  }
  if (lane == 0) out[b] = (float)logtot;
}

extern "C" void kernel_launch(void* const* d_in, const int* in_sizes, int n_in,
                              void* d_out, int out_size, void* d_ws, size_t ws_size,
                              hipStream_t stream) {
  const float* X      = (const float*)d_in[0];
  const float* pi_l   = (const float*)d_in[1];
  const float* tr_l   = (const float*)d_in[2];
  const float* wl     = (const float*)d_in[3];
  const float* means  = (const float*)d_in[4];
  const float* lvs    = (const float*)d_in[5];
  float* out = (float*)d_out;

  float* ws = (float*)d_ws;
  short* Gt      = (short*)ws;                 // 131072 shorts = 65536 f32
  float* const_c = ws + 65536;                 // 512
  short* WTbf    = (short*)(ws + 66048);       // 4096 shorts = 2048 f32
  float* cmaxp   = ws + 68608;                 // 32768
  float* ehat    = ws + 101376;                // 2097152
  short* XeP     = (short*)(ws + 2198528);     // 16 MB
  float* NT      = ws + 2198528;               // aliases XeP (dead after emis); 8388608 f32
  float* aux     = ws + 10587136;              // 4096 (256 chunks x 2 strips x 8 b)
  float* G2T     = ws + 10591232;              // 524288 (8 b x 16 g x 4096)
  float* auxg    = ws + 11115520;              // 128

  mmm_w_kernel<<<64, 64, 0, stream>>>(tr_l, WTbf);
  mmm_prep_kernel<<<512, 128, 0, stream>>>(means, lvs, wl, Gt, const_c);
  mmm_prepxe_kernel<<<512, 256, 0, stream>>>(X, XeP);
  mmm_emis_kernel<<<256, 512, 0, stream>>>(Gt, XeP, const_c, ehat, cmaxp);
  mmm_chunk_kernel<<<dim3(256, 8), 128, 0, stream>>>(WTbf, ehat, cmaxp, NT, aux);
  mmm_merge_kernel<<<dim3(16, 8), 256, 0, stream>>>(NT, aux, G2T, auxg);
  mmm_combine_kernel<<<8, 64, 0, stream>>>(pi_l, ehat, cmaxp, G2T, auxg, out);
}